// Round 5
// baseline (7312.134 us; speedup 1.0000x reference)
//
#include <hip/hip_runtime.h>
#include <hip/hip_fp16.h>
#include <cstddef>

#define NBATCH 16
#define NSIDE  512
#define NT     (NBATCH * NSIDE * NSIDE)   // 4,194,304 complex elements per field
#define NLINES 8                           // FFT lines per workgroup
#define LSTRIDE 577                        // padded float2 stride per line in LDS
#define APACK  (512 * 512)                 // packed capacity (worst case all-active)

constexpr float SIGMA = (float)(0.97 / 3.0);
constexpr float TAU   = (float)(0.97 / 3.0);
constexpr float INV1S = (float)(1.0 / (1.0 + 0.97 / 3.0));
constexpr float INV_N = 1.0f / 512.0f;

// ---------- complex helpers ----------
__device__ __forceinline__ float2 cadd(float2 a, float2 b){ return make_float2(a.x+b.x, a.y+b.y); }
__device__ __forceinline__ float2 csub(float2 a, float2 b){ return make_float2(a.x-b.x, a.y-b.y); }
__device__ __forceinline__ float2 cmul(float2 a, float2 b){ return make_float2(a.x*b.x - a.y*b.y, a.x*b.y + a.y*b.x); }

// padded LDS slot: +1 float2 every 8 slots
__device__ __forceinline__ int SL(int s){ return s + (s >> 3); }
// base-8 3-digit reversal of a 9-bit index
__device__ __forceinline__ int rev9(int s){ return ((s & 7) << 6) | (s & 56) | (s >> 6); }

// fp16 pack/unpack
__device__ __forceinline__ unsigned h2bits(float2 v){
  __half2 h = __floats2half2_rn(v.x, v.y);
  return *reinterpret_cast<unsigned*>(&h);
}
__device__ __forceinline__ float2 bits2f(unsigned u){
  __half2 h = *reinterpret_cast<__half2*>(&u);
  return __half22float2(h);
}
__device__ __forceinline__ float2 clip2(float2 q, float lv){
  return make_float2(fminf(fmaxf(q.x, -lv), lv), fminf(fmaxf(q.y, -lv), lv));
}

template<int S>
__device__ __forceinline__ void dft8(float2 v[8]){
  const float RS = 0.70710678118654752440f;
  float2 a0 = cadd(v[0], v[4]), a4 = csub(v[0], v[4]);
  float2 a1 = cadd(v[1], v[5]), a5 = csub(v[1], v[5]);
  float2 a2 = cadd(v[2], v[6]), a6 = csub(v[2], v[6]);
  float2 a3 = cadd(v[3], v[7]), a7 = csub(v[3], v[7]);
  a5 = cmul(a5, make_float2(RS, (float)S * RS));
  a6 = make_float2(-(float)S * a6.y, (float)S * a6.x);
  a7 = cmul(a7, make_float2(-RS, (float)S * RS));
  float2 b0 = cadd(a0, a2), b2 = csub(a0, a2);
  float2 b1 = cadd(a1, a3), b3 = csub(a1, a3);
  b3 = make_float2(-(float)S * b3.y, (float)S * b3.x);
  v[0] = cadd(b0, b1); v[4] = csub(b0, b1);
  v[2] = cadd(b2, b3); v[6] = csub(b2, b3);
  float2 c0 = cadd(a4, a6), c2 = csub(a4, a6);
  float2 c1 = cadd(a5, a7), c3 = csub(a5, a7);
  c3 = make_float2(-(float)S * c3.y, (float)S * c3.x);
  v[1] = cadd(c0, c1); v[5] = csub(c0, c1);
  v[3] = cadd(c2, c3); v[7] = csub(c2, c3);
}

// Forward 512-pt DIF FFT on two LDS lines (one wave). Natural in, digit-rev out.
__device__ __forceinline__ void fft_fwd_pair(float2* __restrict__ A, float2* __restrict__ B, int l){
  float2 va[8], vb[8];
  #pragma unroll
  for(int j = 0; j < 8; j++){ int s = SL(l + 64*j); va[j] = A[s]; vb[j] = B[s]; }
  dft8<-1>(va); dft8<-1>(vb);
  #pragma unroll
  for(int t = 1; t < 8; t++){
    float sn, cs;
    __sincosf((-6.283185307179586f / 512.0f) * (float)(l * t), &sn, &cs);
    float2 w = make_float2(cs, sn);
    va[t] = cmul(va[t], w); vb[t] = cmul(vb[t], w);
  }
  #pragma unroll
  for(int t = 0; t < 8; t++){ int s = SL(t*64 + l); A[s] = va[t]; B[s] = vb[t]; }
  __syncthreads();
  int tg = l >> 3, m = l & 7;
  #pragma unroll
  for(int j = 0; j < 8; j++){ int s = SL(tg*64 + m + 8*j); va[j] = A[s]; vb[j] = B[s]; }
  dft8<-1>(va); dft8<-1>(vb);
  #pragma unroll
  for(int t = 1; t < 8; t++){
    float sn, cs;
    __sincosf((-6.283185307179586f / 64.0f) * (float)(m * t), &sn, &cs);
    float2 w = make_float2(cs, sn);
    va[t] = cmul(va[t], w); vb[t] = cmul(vb[t], w);
  }
  #pragma unroll
  for(int t = 0; t < 8; t++){ int s = SL(tg*64 + t*8 + m); A[s] = va[t]; B[s] = vb[t]; }
  __syncthreads();
  #pragma unroll
  for(int j = 0; j < 8; j++){ int s = SL(8*l + j); va[j] = A[s]; vb[j] = B[s]; }
  dft8<-1>(va); dft8<-1>(vb);
  #pragma unroll
  for(int t = 0; t < 8; t++){ int s = SL(8*l + t); A[s] = va[t]; B[s] = vb[t]; }
}

// Adjoint 512-pt FFT: digit-rev in, natural out. Exact adjoint of fft_fwd_pair.
__device__ __forceinline__ void fft_inv_pair(float2* __restrict__ A, float2* __restrict__ B, int l){
  float2 va[8], vb[8];
  #pragma unroll
  for(int j = 0; j < 8; j++){ int s = SL(8*l + j); va[j] = A[s]; vb[j] = B[s]; }
  dft8<1>(va); dft8<1>(vb);
  #pragma unroll
  for(int t = 0; t < 8; t++){ int s = SL(8*l + t); A[s] = va[t]; B[s] = vb[t]; }
  __syncthreads();
  int tg = l >> 3, m = l & 7;
  #pragma unroll
  for(int j = 0; j < 8; j++){ int s = SL(tg*64 + 8*j + m); va[j] = A[s]; vb[j] = B[s]; }
  #pragma unroll
  for(int j = 1; j < 8; j++){
    float sn, cs;
    __sincosf((6.283185307179586f / 64.0f) * (float)(m * j), &sn, &cs);
    float2 w = make_float2(cs, sn);
    va[j] = cmul(va[j], w); vb[j] = cmul(vb[j], w);
  }
  dft8<1>(va); dft8<1>(vb);
  #pragma unroll
  for(int j = 0; j < 8; j++){ int s = SL(tg*64 + m + 8*j); A[s] = va[j]; B[s] = vb[j]; }
  __syncthreads();
  #pragma unroll
  for(int t = 0; t < 8; t++){ int s = SL(t*64 + l); va[t] = A[s]; vb[t] = B[s]; }
  #pragma unroll
  for(int t = 1; t < 8; t++){
    float sn, cs;
    __sincosf((6.283185307179586f / 512.0f) * (float)(l * t), &sn, &cs);
    float2 w = make_float2(cs, sn);
    va[t] = cmul(va[t], w); vb[t] = cmul(vb[t], w);
  }
  dft8<1>(va); dft8<1>(vb);
  #pragma unroll
  for(int j = 0; j < 8; j++){ int s = SL(l + 64*j); A[s] = va[j]; B[s] = vb[j]; }
}

// Blocked-tile store: tile holds 512 x 8 fp16 complex, element s*8 + line.
__device__ __forceinline__ void store_strip_blk(const float2* __restrict__ lds, __half2* __restrict__ tile, int t){
  int q = t & 3, s0v = t >> 2;   // s0v 0..63
  #pragma unroll
  for(int k = 0; k < 8; k++){
    int s = s0v + 64 * k;
    float2 v0 = lds[(2*q)   * LSTRIDE + SL(s)];
    float2 v1 = lds[(2*q+1) * LSTRIDE + SL(s)];
    uint2 u; u.x = h2bits(v0); u.y = h2bits(v1);
    *reinterpret_cast<uint2*>(tile + s*8 + 2*q) = u;
  }
}

// Blocked-tile load into LDS lines: 64 tiles of 512x8; line g reads tile row (lineBase+g).
__device__ __forceinline__ void load_strip_blk(float2* __restrict__ lds, const __half2* __restrict__ base,
                                               int lineBase, int t){
  #pragma unroll
  for(int k = 0; k < 4; k++){
    int idx = t + 256 * k;        // 0..1023
    int tb = idx >> 4;            // tile 0..63
    int rem = idx & 15;
    int g = rem >> 1, h = rem & 1;
    uint4 u = *reinterpret_cast<const uint4*>(base + ((size_t)tb << 12) + ((lineBase + g) << 3) + (h << 2));
    int n = (tb << 3) + (h << 2);
    lds[g * LSTRIDE + SL(n)]     = bits2f(u.x);
    lds[g * LSTRIDE + SL(n + 1)] = bits2f(u.y);
    lds[g * LSTRIDE + SL(n + 2)] = bits2f(u.z);
    lds[g * LSTRIDE + SL(n + 3)] = bits2f(u.w);
  }
}

// ---------------- prologue: forward row FFT of S*x0/512 -> U (fp16, blocked) -----------------
__global__ __launch_bounds__(256) void k_fwd_rows(const float* __restrict__ ir, const float* __restrict__ ii,
                                                  __half2* __restrict__ U){
  __shared__ float2 lds[NLINES * LSTRIDE];
  int b = blockIdx.x >> 6, rb = blockIdx.x & 63, r0 = rb << 3;
  int t = threadIdx.x;
  int rr = t >> 5, col = t & 31;
  size_t base = ((size_t)(b * 512 + r0 + rr) << 9);
  #pragma unroll
  for(int k = 0; k < 16; k++){
    int c = col + 32 * k;
    float sc = ((r0 + rr + c) & 1) ? -INV_N : INV_N;
    lds[rr * LSTRIDE + SL(c)] = make_float2(sc * ir[base + c], sc * ii[base + c]);
  }
  __syncthreads();
  int wv = t >> 6, l = t & 63;
  fft_fwd_pair(&lds[wv * LSTRIDE], &lds[(wv + 4) * LSTRIDE], l);
  __syncthreads();
  store_strip_blk(lds, U + ((size_t)(b * 64 + rb) << 12), t);
}

// ---- K_A: column fwd FFT + packed p1 prox + column inv FFT -> V (pure k-space kernel) -------
__global__ __launch_bounds__(256) void k_colsA(const __half2* __restrict__ U, __half2* __restrict__ p1p,
                                               const __half2* __restrict__ yp, const int* __restrict__ idx,
                                               const int* __restrict__ cnt, __half2* __restrict__ V){
  __shared__ float2 lds[NLINES * LSTRIDE];
  int b = blockIdx.x >> 6, cb = blockIdx.x & 63, cs0 = cb << 3;
  int t = threadIdx.x;
  int rr = t >> 5, col = t & 31;
  load_strip_blk(lds, U + ((size_t)b << 18), cs0, t);
  __syncthreads();
  int wv = t >> 6, l = t & 63;
  fft_fwd_pair(&lds[wv * LSTRIDE], &lds[(wv + 4) * LSTRIDE], l);
  __syncthreads();
  // packed p1 update: line g handles column cs0+g, segment [cs*512, cs*512+cnt[cs])
  int g = rr, lane = col;
  int cs = cs0 + g;
  int jbase = cs << 9;
  int jcnt = cnt[cs];
  size_t boff = (size_t)b * APACK;
  int ksi[16]; float2 pn[16];
  #pragma unroll
  for(int tt = 0; tt < 16; tt++){
    int jj = lane + 32 * tt;
    bool act = jj < jcnt;
    int j = jbase + (act ? jj : 0);
    int ks = act ? idx[j] : 0;
    float2 K = lds[g * LSTRIDE + SL(ks)];
    float2 yv = __half22float2(yp[boff + j]);
    float2 p  = __half22float2(p1p[boff + j]);
    float2 v;
    v.x = (p.x + SIGMA * (K.x - yv.x)) * INV1S;
    v.y = (p.y + SIGMA * (K.y - yv.y)) * INV1S;
    if(act) p1p[boff + j] = __floats2half2_rn(v.x, v.y);
    ksi[tt] = act ? ks : -1;
    pn[tt] = v;
  }
  __syncthreads();
  #pragma unroll
  for(int k = 0; k < 16; k++) lds[rr * LSTRIDE + SL(col + 32 * k)] = make_float2(0.0f, 0.0f);
  __syncthreads();
  #pragma unroll
  for(int tt = 0; tt < 16; tt++) if(ksi[tt] >= 0) lds[g * LSTRIDE + SL(ksi[tt])] = pn[tt];
  __syncthreads();
  fft_inv_pair(&lds[wv * LSTRIDE], &lds[(wv + 4) * LSTRIDE], l);
  __syncthreads();
  store_strip_blk(lds, V + ((size_t)(b * 64 + cb) << 12), t);
}

// ------- K_B: row IFFT + fused TV-dual update (halo recompute) + divergence + primal ---------
//         update + extrapolation + row FFT -> U.  p2 and xbar are ping-ponged (src/dst).
__global__ __launch_bounds__(256) void k_megaB(const __half2* __restrict__ V,
                                               const __half2* __restrict__ p2h_s, const __half2* __restrict__ p2w_s,
                                               __half2* __restrict__ p2h_d, __half2* __restrict__ p2w_d,
                                               const __half2* __restrict__ xb_s, __half2* __restrict__ xb_d,
                                               __half2* __restrict__ xh, const __half* __restrict__ lamh,
                                               __half2* __restrict__ U, float2* __restrict__ xout, int last){
  __shared__ float2 lds[NLINES * LSTRIDE];
  int b = blockIdx.x >> 6, rb = blockIdx.x & 63, r0 = rb << 3;
  int t = threadIdx.x;
  int rr = t >> 5, col = t & 31;
  load_strip_blk(lds, V + ((size_t)b << 18), r0, t);
  __syncthreads();
  int wv = t >> 6, l = t & 63;
  fft_inv_pair(&lds[wv * LSTRIDE], &lds[(wv + 4) * LSTRIDE], l);
  __syncthreads();
  int r = r0 + rr;
  size_t ibase = ((size_t)(b * 512 + r) << 9);
  size_t ibUp  = ((size_t)(b * 512 + ((r - 1) & 511)) << 9);
  size_t ibDn  = ((size_t)(b * 512 + ((r + 1) & 511)) << 9);
  #pragma unroll
  for(int k = 0; k < 16; k++){
    int c = col + 32 * k;
    int cl = (c - 1) & 511, cr = (c + 1) & 511;
    // xbar neighborhood (fp16 source, prev iteration's extrapolation)
    float2 xc = __half22float2(xb_s[ibase + c]);
    float2 xR = __half22float2(xb_s[ibase + cr]);
    float2 xL = __half22float2(xb_s[ibase + cl]);
    float2 xU = __half22float2(xb_s[ibUp + c]);
    float2 xD = __half22float2(xb_s[ibDn + c]);
    float lv  = __half2float(lamh[ibase + c]);
    float lvU = __half2float(lamh[ibUp + c]);
    float lvL = __half2float(lamh[ibase + cl]);
    // dual updates: own (written) + halo (recomputed, deterministic, owner writes elsewhere)
    float2 hn  = clip2(make_float2(0,0), 0); // placeholder to keep compiler happy
    {
      float2 ho = __half22float2(p2h_s[ibase + c]);
      hn = clip2(make_float2(ho.x + SIGMA * (xD.x - xc.x), ho.y + SIGMA * (xD.y - xc.y)), lv);
    }
    float2 hUn;
    {
      float2 hu = __half22float2(p2h_s[ibUp + c]);
      hUn = clip2(make_float2(hu.x + SIGMA * (xc.x - xU.x), hu.y + SIGMA * (xc.y - xU.y)), lvU);
    }
    float2 wn;
    {
      float2 wo = __half22float2(p2w_s[ibase + c]);
      wn = clip2(make_float2(wo.x + SIGMA * (xR.x - xc.x), wo.y + SIGMA * (xR.y - xc.y)), lv);
    }
    float2 wLn;
    {
      float2 wl = __half22float2(p2w_s[ibase + cl]);
      wLn = clip2(make_float2(wl.x + SIGMA * (xc.x - xL.x), wl.y + SIGMA * (xc.y - xL.y)), lvL);
    }
    p2h_d[ibase + c] = __floats2half2_rn(hn.x, hn.y);
    p2w_d[ibase + c] = __floats2half2_rn(wn.x, wn.y);
    // divergence + primal descent + extrapolation
    float2 v = lds[rr * LSTRIDE + SL(c)];
    float sc = ((r + c) & 1) ? -INV_N : INV_N;
    float gx = sc * v.x + (hUn.x - hn.x) + (wLn.x - wn.x);
    float gy = sc * v.y + (hUn.y - hn.y) + (wLn.y - wn.y);
    float2 xo = __half22float2(xh[ibase + c]);
    float2 xn = make_float2(xo.x - TAU * gx, xo.y - TAU * gy);
    xh[ibase + c] = __floats2half2_rn(xn.x, xn.y);
    float2 xb2 = make_float2(2.0f * xn.x - xo.x, 2.0f * xn.y - xo.y);
    xb_d[ibase + c] = __floats2half2_rn(xb2.x, xb2.y);
    if(last) xout[ibase + c] = xn;
    lds[rr * LSTRIDE + SL(c)] = make_float2(sc * xb2.x, sc * xb2.y);  // S*xbar/512 for next fwd FFT
  }
  if(last) return;
  __syncthreads();
  fft_fwd_pair(&lds[wv * LSTRIDE], &lds[(wv + 4) * LSTRIDE], l);
  __syncthreads();
  store_strip_blk(lds, U + ((size_t)(b * 64 + rb) << 12), t);
}

// ---------------- init kernels ---------------------------------------------------------------
__global__ __launch_bounds__(256) void k_init_x(const float* __restrict__ ir, const float* __restrict__ ii,
                                                __half2* __restrict__ xh, __half2* __restrict__ xb0){
  int i = blockIdx.x * 256 + threadIdx.x;
  __half2 v = __floats2half2_rn(ir[i], ii[i]);
  xh[i] = v; xb0[i] = v;
}

__global__ __launch_bounds__(256) void k_init_lam(const float* __restrict__ lam, __half* __restrict__ lamh){
  int i = blockIdx.x * 256 + threadIdx.x;
  lamh[i] = __float2half(lam[i]);
}

// Build per-column packed index list + packed y' (digit-rev, S-folded, fp16) for active entries.
__global__ __launch_bounds__(256) void k_pack(const int* __restrict__ mask, const float* __restrict__ kr,
                                              const float* __restrict__ ki, int* __restrict__ idx,
                                              int* __restrict__ cnt, __half2* __restrict__ yp){
  __shared__ int wcnt[8];
  int cs = blockIdx.x;
  int t = threadIdx.x, lane = t & 63, wv = t >> 6;
  int csr = rev9(cs);
  int jbase = cs << 9;
  #pragma unroll
  for(int rnd = 0; rnd < 2; rnd++){
    int ks = t + 256 * rnd;
    int ksr = rev9(ks);
    int pred = (mask[(ksr << 9) + csr] != 0) ? 1 : 0;
    unsigned long long bal = __ballot(pred);
    if(lane == 0) wcnt[4 * rnd + wv] = (int)__popcll(bal);
    __syncthreads();
    int pre = 0;
    for(int w = 0; w < wv; w++) pre += wcnt[4 * rnd + w];
    int roundbase = (rnd == 1) ? (wcnt[0] + wcnt[1] + wcnt[2] + wcnt[3]) : 0;
    int lpre = (int)__popcll(bal & ((1ull << lane) - 1ull));
    if(pred){
      int pos = jbase + roundbase + pre + lpre;
      idx[pos] = ks;
      float s = ((ksr + csr) & 1) ? -1.0f : 1.0f;
      for(int b = 0; b < 16; b++){
        size_t a = ((size_t)b << 18) + ((size_t)ksr << 9) + csr;
        yp[(size_t)b * APACK + pos] = __floats2half2_rn(s * kr[a], s * ki[a]);
      }
    }
    __syncthreads();
  }
  if(t == 0) cnt[cs] = wcnt[0] + wcnt[1] + wcnt[2] + wcnt[3] + wcnt[4] + wcnt[5] + wcnt[6] + wcnt[7];
}

// ---------------- launcher -------------------------------------------------------------------
extern "C" void kernel_launch(void* const* d_in, const int* in_sizes, int n_in,
                              void* d_out, int out_size, void* d_ws, size_t ws_size,
                              hipStream_t stream){
  const float* ir  = (const float*)d_in[0];
  const float* ii  = (const float*)d_in[1];
  const float* kdr = (const float*)d_in[2];
  const float* kdi = (const float*)d_in[3];
  const float* lam = (const float*)d_in[4];
  const int*  mask = (const int*)d_in[5];
  float2* x = (float2*)d_out;

  char* ws = (char*)d_ws;
  __half2* p1p   = (__half2*)ws;                     // 16 MB
  __half2* yp    = p1p + (size_t)APACK * 16;         // 16 MB
  __half2* p2h0  = yp  + (size_t)APACK * 16;         // 16 MB  (zeroed; contiguous w/ p2w0)
  __half2* p2w0  = p2h0 + NT;                        // 16 MB
  __half2* p2h1  = p2w0 + NT;                        // 16 MB
  __half2* p2w1  = p2h1 + NT;                        // 16 MB
  __half2* xb0   = p2w1 + NT;                        // 16 MB
  __half2* xb1   = xb0 + NT;                         // 16 MB
  __half2* xh    = xb1 + NT;                         // 16 MB (fp16 primal state)
  __half2* U     = xh  + NT;                         // 16 MB (blocked tiles)
  __half2* V     = U   + NT;                         // 16 MB (blocked tiles)
  __half*  lamh  = (__half*)(V + NT);                // 8 MB
  int*     idx   = (int*)(lamh + NT);                // 1 MB
  int*     cnt   = idx + APACK;                      // 2 KB
  // total ws use: ~185 MB (round-0 proved ≥236 MB available)

  hipMemsetAsync(p1p, 0, (size_t)APACK * 16 * sizeof(__half2), stream);   // p1 = 0
  hipMemsetAsync(p2h0, 0, (size_t)2 * NT * sizeof(__half2), stream);      // p2h0 + p2w0 = 0
  k_pack<<<512, 256, 0, stream>>>(mask, kdr, kdi, idx, cnt, yp);
  k_init_lam<<<NT / 256, 256, 0, stream>>>(lam, lamh);
  k_init_x<<<NT / 256, 256, 0, stream>>>(ir, ii, xh, xb0);
  k_fwd_rows<<<1024, 256, 0, stream>>>(ir, ii, U);

  __half2* p2hs[2] = {p2h0, p2h1};
  __half2* p2ws[2] = {p2w0, p2w1};
  __half2* xbs[2]  = {xb0, xb1};

  for(int it = 0; it < 128; it++){
    int s = it & 1, d = s ^ 1;
    k_colsA<<<1024, 256, 0, stream>>>(U, p1p, yp, idx, cnt, V);
    k_megaB<<<1024, 256, 0, stream>>>(V, p2hs[s], p2ws[s], p2hs[d], p2ws[d],
                                      xbs[s], xbs[d], xh, lamh, U, x, it == 127 ? 1 : 0);
  }
}

// Round 6
// 6967.271 us; speedup vs baseline: 1.0495x; 1.0495x over previous
//
#include <hip/hip_runtime.h>
#include <hip/hip_fp16.h>
#include <cstddef>

#define NBATCH 16
#define NSIDE  512
#define NT     (NBATCH * NSIDE * NSIDE)   // 4,194,304 complex elements per field
#define NLINES 8                           // FFT lines per workgroup
#define LSTRIDE 577                        // padded float2 stride per line in LDS
#define APACK  (512 * 512)                 // packed capacity (worst case all-active)

constexpr float SIGMA = (float)(0.97 / 3.0);
constexpr float TAU   = (float)(0.97 / 3.0);
constexpr float INV1S = (float)(1.0 / (1.0 + 0.97 / 3.0));
constexpr float INV_N = 1.0f / 512.0f;

// ---------- complex helpers ----------
__device__ __forceinline__ float2 cadd(float2 a, float2 b){ return make_float2(a.x+b.x, a.y+b.y); }
__device__ __forceinline__ float2 csub(float2 a, float2 b){ return make_float2(a.x-b.x, a.y-b.y); }
__device__ __forceinline__ float2 cmul(float2 a, float2 b){ return make_float2(a.x*b.x - a.y*b.y, a.x*b.y + a.y*b.x); }
// a * conj(b)
__device__ __forceinline__ float2 cmulc(float2 a, float2 b){ return make_float2(a.x*b.x + a.y*b.y, a.y*b.x - a.x*b.y); }

// padded LDS slot: +1 float2 every 8 slots
__device__ __forceinline__ int SL(int s){ return s + (s >> 3); }
// base-8 3-digit reversal of a 9-bit index
__device__ __forceinline__ int rev9(int s){ return ((s & 7) << 6) | (s & 56) | (s >> 6); }

// fp16 pack/unpack
__device__ __forceinline__ unsigned h2bits(float2 v){
  __half2 h = __floats2half2_rn(v.x, v.y);
  return *reinterpret_cast<unsigned*>(&h);
}
__device__ __forceinline__ float2 bits2f(unsigned u){
  __half2 h = *reinterpret_cast<__half2*>(&u);
  return __half22float2(h);
}
__device__ __forceinline__ float2 clip2(float2 q, float lv){
  return make_float2(fminf(fmaxf(q.x, -lv), lv), fminf(fmaxf(q.y, -lv), lv));
}

template<int S>
__device__ __forceinline__ void dft8(float2 v[8]){
  const float RS = 0.70710678118654752440f;
  float2 a0 = cadd(v[0], v[4]), a4 = csub(v[0], v[4]);
  float2 a1 = cadd(v[1], v[5]), a5 = csub(v[1], v[5]);
  float2 a2 = cadd(v[2], v[6]), a6 = csub(v[2], v[6]);
  float2 a3 = cadd(v[3], v[7]), a7 = csub(v[3], v[7]);
  a5 = cmul(a5, make_float2(RS, (float)S * RS));
  a6 = make_float2(-(float)S * a6.y, (float)S * a6.x);
  a7 = cmul(a7, make_float2(-RS, (float)S * RS));
  float2 b0 = cadd(a0, a2), b2 = csub(a0, a2);
  float2 b1 = cadd(a1, a3), b3 = csub(a1, a3);
  b3 = make_float2(-(float)S * b3.y, (float)S * b3.x);
  v[0] = cadd(b0, b1); v[4] = csub(b0, b1);
  v[2] = cadd(b2, b3); v[6] = csub(b2, b3);
  float2 c0 = cadd(a4, a6), c2 = csub(a4, a6);
  float2 c1 = cadd(a5, a7), c3 = csub(a5, a7);
  c3 = make_float2(-(float)S * c3.y, (float)S * c3.x);
  v[1] = cadd(c0, c1); v[5] = csub(c0, c1);
  v[3] = cadd(c2, c3); v[7] = csub(c2, c3);
}

// Twiddle table (global, L1-hot): tw[l*8+t] = exp(-2*pi*i*l*t/512) for l<64, t=1..7;
// tw[512 + m*8 + t] = exp(-2*pi*i*m*t/64) for m<8, t=1..7.
// Forward 512-pt DIF FFT on two LDS lines (one wave). Natural in, digit-rev out.
__device__ __forceinline__ void fft_fwd_pair(float2* __restrict__ A, float2* __restrict__ B, int l,
                                             const float2* __restrict__ twid){
  float2 va[8], vb[8];
  const float2* t1 = twid + l * 8;
  const float2* t2 = twid + 512 + (l & 7) * 8;
  #pragma unroll
  for(int j = 0; j < 8; j++){ int s = SL(l + 64*j); va[j] = A[s]; vb[j] = B[s]; }
  dft8<-1>(va); dft8<-1>(vb);
  #pragma unroll
  for(int t = 1; t < 8; t++){
    float2 w = t1[t];
    va[t] = cmul(va[t], w); vb[t] = cmul(vb[t], w);
  }
  #pragma unroll
  for(int t = 0; t < 8; t++){ int s = SL(t*64 + l); A[s] = va[t]; B[s] = vb[t]; }
  __syncthreads();
  int tg = l >> 3, m = l & 7;
  #pragma unroll
  for(int j = 0; j < 8; j++){ int s = SL(tg*64 + m + 8*j); va[j] = A[s]; vb[j] = B[s]; }
  dft8<-1>(va); dft8<-1>(vb);
  #pragma unroll
  for(int t = 1; t < 8; t++){
    float2 w = t2[t];
    va[t] = cmul(va[t], w); vb[t] = cmul(vb[t], w);
  }
  #pragma unroll
  for(int t = 0; t < 8; t++){ int s = SL(tg*64 + t*8 + m); A[s] = va[t]; B[s] = vb[t]; }
  __syncthreads();
  #pragma unroll
  for(int j = 0; j < 8; j++){ int s = SL(8*l + j); va[j] = A[s]; vb[j] = B[s]; }
  dft8<-1>(va); dft8<-1>(vb);
  #pragma unroll
  for(int t = 0; t < 8; t++){ int s = SL(8*l + t); A[s] = va[t]; B[s] = vb[t]; }
}

// Adjoint 512-pt FFT: digit-rev in, natural out. Exact adjoint of fft_fwd_pair.
__device__ __forceinline__ void fft_inv_pair(float2* __restrict__ A, float2* __restrict__ B, int l,
                                             const float2* __restrict__ twid){
  float2 va[8], vb[8];
  const float2* t1 = twid + l * 8;
  const float2* t2 = twid + 512 + (l & 7) * 8;
  #pragma unroll
  for(int j = 0; j < 8; j++){ int s = SL(8*l + j); va[j] = A[s]; vb[j] = B[s]; }
  dft8<1>(va); dft8<1>(vb);
  #pragma unroll
  for(int t = 0; t < 8; t++){ int s = SL(8*l + t); A[s] = va[t]; B[s] = vb[t]; }
  __syncthreads();
  int tg = l >> 3, m = l & 7;
  #pragma unroll
  for(int j = 0; j < 8; j++){ int s = SL(tg*64 + 8*j + m); va[j] = A[s]; vb[j] = B[s]; }
  #pragma unroll
  for(int j = 1; j < 8; j++){
    float2 w = t2[j];
    va[j] = cmulc(va[j], w); vb[j] = cmulc(vb[j], w);
  }
  dft8<1>(va); dft8<1>(vb);
  #pragma unroll
  for(int j = 0; j < 8; j++){ int s = SL(tg*64 + m + 8*j); A[s] = va[j]; B[s] = vb[j]; }
  __syncthreads();
  #pragma unroll
  for(int t = 0; t < 8; t++){ int s = SL(t*64 + l); va[t] = A[s]; vb[t] = B[s]; }
  #pragma unroll
  for(int t = 1; t < 8; t++){
    float2 w = t1[t];
    va[t] = cmulc(va[t], w); vb[t] = cmulc(vb[t], w);
  }
  dft8<1>(va); dft8<1>(vb);
  #pragma unroll
  for(int j = 0; j < 8; j++){ int s = SL(l + 64*j); A[s] = va[j]; B[s] = vb[j]; }
}

// Blocked-tile store: tile holds 512 x 8 fp16 complex, element s*8 + line.
__device__ __forceinline__ void store_strip_blk(const float2* __restrict__ lds, __half2* __restrict__ tile, int t){
  int q = t & 3, s0v = t >> 2;   // s0v 0..63
  #pragma unroll
  for(int k = 0; k < 8; k++){
    int s = s0v + 64 * k;
    float2 v0 = lds[(2*q)   * LSTRIDE + SL(s)];
    float2 v1 = lds[(2*q+1) * LSTRIDE + SL(s)];
    uint2 u; u.x = h2bits(v0); u.y = h2bits(v1);
    *reinterpret_cast<uint2*>(tile + s*8 + 2*q) = u;
  }
}

// Blocked-tile load into LDS lines: 64 tiles of 512x8; line g reads tile row (lineBase+g).
__device__ __forceinline__ void load_strip_blk(float2* __restrict__ lds, const __half2* __restrict__ base,
                                               int lineBase, int t){
  #pragma unroll
  for(int k = 0; k < 4; k++){
    int idx = t + 256 * k;        // 0..1023
    int tb = idx >> 4;            // tile 0..63
    int rem = idx & 15;
    int g = rem >> 1, h = rem & 1;
    uint4 u = *reinterpret_cast<const uint4*>(base + ((size_t)tb << 12) + ((lineBase + g) << 3) + (h << 2));
    int n = (tb << 3) + (h << 2);
    lds[g * LSTRIDE + SL(n)]     = bits2f(u.x);
    lds[g * LSTRIDE + SL(n + 1)] = bits2f(u.y);
    lds[g * LSTRIDE + SL(n + 2)] = bits2f(u.z);
    lds[g * LSTRIDE + SL(n + 3)] = bits2f(u.w);
  }
}

// ---------------- prologue: forward row FFT of S*x0/512 -> U (fp16, blocked) -----------------
__global__ __launch_bounds__(256) void k_fwd_rows(const float* __restrict__ ir, const float* __restrict__ ii,
                                                  __half2* __restrict__ U, const float2* __restrict__ twid){
  __shared__ float2 lds[NLINES * LSTRIDE];
  int b = blockIdx.x >> 6, rb = blockIdx.x & 63, r0 = rb << 3;
  int t = threadIdx.x;
  int rr = t >> 5, col = t & 31;
  size_t base = ((size_t)(b * 512 + r0 + rr) << 9);
  #pragma unroll
  for(int k = 0; k < 16; k++){
    int c = col + 32 * k;
    float sc = ((r0 + rr + c) & 1) ? -INV_N : INV_N;
    lds[rr * LSTRIDE + SL(c)] = make_float2(sc * ir[base + c], sc * ii[base + c]);
  }
  __syncthreads();
  int wv = t >> 6, l = t & 63;
  fft_fwd_pair(&lds[wv * LSTRIDE], &lds[(wv + 4) * LSTRIDE], l, twid);
  __syncthreads();
  store_strip_blk(lds, U + ((size_t)(b * 64 + rb) << 12), t);
}

// ---- K_A: column fwd FFT + packed p1 prox + column inv FFT -> V (pure k-space kernel) -------
__global__ __launch_bounds__(256) void k_colsA(const __half2* __restrict__ U, __half2* __restrict__ p1p,
                                               const __half2* __restrict__ yp, const int* __restrict__ idx,
                                               const int* __restrict__ cnt, __half2* __restrict__ V,
                                               const float2* __restrict__ twid){
  __shared__ float2 lds[NLINES * LSTRIDE];
  int b = blockIdx.x >> 6, cb = blockIdx.x & 63, cs0 = cb << 3;
  int t = threadIdx.x;
  int rr = t >> 5, col = t & 31;
  load_strip_blk(lds, U + ((size_t)b << 18), cs0, t);
  __syncthreads();
  int wv = t >> 6, l = t & 63;
  fft_fwd_pair(&lds[wv * LSTRIDE], &lds[(wv + 4) * LSTRIDE], l, twid);
  __syncthreads();
  // packed p1 update (pair-vectorized): line g handles column cs0+g
  int g = rr, lane = col;
  int cs = cs0 + g;
  int jbase = cs << 9;
  int jcnt = cnt[cs];
  size_t boff = (size_t)b * APACK;
  int ks0a[8], ks1a[8]; float2 pn0a[8], pn1a[8];
  #pragma unroll
  for(int tt = 0; tt < 8; tt++){
    int j0 = 2 * lane + 64 * tt;
    bool a0 = j0 < jcnt, a1 = (j0 + 1) < jcnt;
    size_t jj = boff + jbase + j0;
    int2  ip = *reinterpret_cast<const int2*>(idx + jbase + j0);
    uint2 yu = *reinterpret_cast<const uint2*>(yp + jj);
    uint2 pu = *reinterpret_cast<const uint2*>(p1p + jj);
    int ks0 = a0 ? ip.x : 0, ks1 = a1 ? ip.y : 0;
    float2 K0 = lds[g * LSTRIDE + SL(ks0)];
    float2 K1 = lds[g * LSTRIDE + SL(ks1)];
    float2 y0 = bits2f(yu.x), y1 = bits2f(yu.y);
    float2 p0 = bits2f(pu.x), p1v = bits2f(pu.y);
    float2 v0, v1;
    v0.x = (p0.x + SIGMA * (K0.x - y0.x)) * INV1S;
    v0.y = (p0.y + SIGMA * (K0.y - y0.y)) * INV1S;
    v1.x = (p1v.x + SIGMA * (K1.x - y1.x)) * INV1S;
    v1.y = (p1v.y + SIGMA * (K1.y - y1.y)) * INV1S;
    uint2 st; st.x = h2bits(v0); st.y = h2bits(v1);
    if(a1)      *reinterpret_cast<uint2*>(p1p + jj) = st;
    else if(a0) *reinterpret_cast<unsigned*>(p1p + jj) = st.x;
    ks0a[tt] = a0 ? ks0 : -1; ks1a[tt] = a1 ? ks1 : -1;
    pn0a[tt] = v0; pn1a[tt] = v1;
  }
  __syncthreads();
  #pragma unroll
  for(int k = 0; k < 16; k++) lds[rr * LSTRIDE + SL(col + 32 * k)] = make_float2(0.0f, 0.0f);
  __syncthreads();
  #pragma unroll
  for(int tt = 0; tt < 8; tt++){
    if(ks0a[tt] >= 0) lds[g * LSTRIDE + SL(ks0a[tt])] = pn0a[tt];
    if(ks1a[tt] >= 0) lds[g * LSTRIDE + SL(ks1a[tt])] = pn1a[tt];
  }
  __syncthreads();
  fft_inv_pair(&lds[wv * LSTRIDE], &lds[(wv + 4) * LSTRIDE], l, twid);
  __syncthreads();
  store_strip_blk(lds, V + ((size_t)(b * 64 + cb) << 12), t);
}

// ------- K_B: row IFFT + fused TV-dual update (halo recompute) + divergence + primal ---------
//         update + extrapolation + row FFT -> U.  p2 and xbar ping-ponged.  Pair-vectorized.
__global__ __launch_bounds__(256) void k_megaB(const __half2* __restrict__ V,
                                               const __half2* __restrict__ p2h_s, const __half2* __restrict__ p2w_s,
                                               __half2* __restrict__ p2h_d, __half2* __restrict__ p2w_d,
                                               const __half2* __restrict__ xb_s, __half2* __restrict__ xb_d,
                                               __half2* __restrict__ xh, const __half* __restrict__ lamh,
                                               __half2* __restrict__ U, float2* __restrict__ xout,
                                               const float2* __restrict__ twid, int last){
  __shared__ float2 lds[NLINES * LSTRIDE];
  int b = blockIdx.x >> 6, rb = blockIdx.x & 63, r0 = rb << 3;
  int t = threadIdx.x;
  int rr = t >> 5, col = t & 31;
  load_strip_blk(lds, V + ((size_t)b << 18), r0, t);
  __syncthreads();
  int wv = t >> 6, l = t & 63;
  fft_inv_pair(&lds[wv * LSTRIDE], &lds[(wv + 4) * LSTRIDE], l, twid);
  __syncthreads();
  int r = r0 + rr;
  size_t ib  = ((size_t)(b * 512 + r) << 9);
  size_t ibU = ((size_t)(b * 512 + ((r - 1) & 511)) << 9);
  size_t ibD = ((size_t)(b * 512 + ((r + 1) & 511)) << 9);
  float sc0 = (r & 1) ? -INV_N : INV_N;   // c0 even -> parity depends on r only
  float sc1 = -sc0;
  #pragma unroll
  for(int k = 0; k < 8; k++){
    int c0 = 2 * col + 64 * k;            // even
    int clm = (c0 - 1) & 511;
    int crp = (c0 + 2) & 511;
    // -------- pair loads (8B) + scalar halos (4B/2B) --------
    uint2 xo_u = *reinterpret_cast<const uint2*>(xb_s + ib  + c0);
    uint2 xu_u = *reinterpret_cast<const uint2*>(xb_s + ibU + c0);
    uint2 xd_u = *reinterpret_cast<const uint2*>(xb_s + ibD + c0);
    unsigned xl_u = *reinterpret_cast<const unsigned*>(xb_s + ib + clm);
    unsigned xr_u = *reinterpret_cast<const unsigned*>(xb_s + ib + crp);
    uint2 h_u  = *reinterpret_cast<const uint2*>(p2h_s + ib  + c0);
    uint2 hU_u = *reinterpret_cast<const uint2*>(p2h_s + ibU + c0);
    uint2 w_u  = *reinterpret_cast<const uint2*>(p2w_s + ib  + c0);
    unsigned wL_u = *reinterpret_cast<const unsigned*>(p2w_s + ib + clm);
    unsigned lam_u  = *reinterpret_cast<const unsigned*>(lamh + ib  + c0);
    unsigned lamU_u = *reinterpret_cast<const unsigned*>(lamh + ibU + c0);
    float lvL = __half2float(lamh[ib + clm]);
    uint2 xh_u = *reinterpret_cast<const uint2*>(xh + ib + c0);
    // -------- unpack --------
    float2 x0 = bits2f(xo_u.x), x1 = bits2f(xo_u.y);
    float2 xU0 = bits2f(xu_u.x), xU1 = bits2f(xu_u.y);
    float2 xD0 = bits2f(xd_u.x), xD1 = bits2f(xd_u.y);
    float2 xL = bits2f(xl_u), xRt = bits2f(xr_u);
    float2 h0 = bits2f(h_u.x), h1 = bits2f(h_u.y);
    float2 hU0 = bits2f(hU_u.x), hU1 = bits2f(hU_u.y);
    float2 w0 = bits2f(w_u.x), w1 = bits2f(w_u.y);
    float2 wL = bits2f(wL_u);
    float2 lp = bits2f(lam_u);    // (lam[c0], lam[c0+1])
    float2 lpU = bits2f(lamU_u);
    // -------- dual updates (own + recomputed halos) --------
    float2 hn0 = clip2(make_float2(h0.x + SIGMA*(xD0.x - x0.x), h0.y + SIGMA*(xD0.y - x0.y)), lp.x);
    float2 hn1 = clip2(make_float2(h1.x + SIGMA*(xD1.x - x1.x), h1.y + SIGMA*(xD1.y - x1.y)), lp.y);
    float2 hUn0 = clip2(make_float2(hU0.x + SIGMA*(x0.x - xU0.x), hU0.y + SIGMA*(x0.y - xU0.y)), lpU.x);
    float2 hUn1 = clip2(make_float2(hU1.x + SIGMA*(x1.x - xU1.x), hU1.y + SIGMA*(x1.y - xU1.y)), lpU.y);
    float2 wn0 = clip2(make_float2(w0.x + SIGMA*(x1.x - x0.x), w0.y + SIGMA*(x1.y - x0.y)), lp.x);
    float2 wn1 = clip2(make_float2(w1.x + SIGMA*(xRt.x - x1.x), w1.y + SIGMA*(xRt.y - x1.y)), lp.y);
    float2 wLn0 = clip2(make_float2(wL.x + SIGMA*(x0.x - xL.x), wL.y + SIGMA*(x0.y - xL.y)), lvL);
    float2 wLn1 = wn0;
    // -------- divergence + primal + extrapolation --------
    float2 v0 = lds[rr * LSTRIDE + SL(c0)];
    float2 v1 = lds[rr * LSTRIDE + SL(c0 + 1)];
    float gx0 = sc0 * v0.x + (hUn0.x - hn0.x) + (wLn0.x - wn0.x);
    float gy0 = sc0 * v0.y + (hUn0.y - hn0.y) + (wLn0.y - wn0.y);
    float gx1 = sc1 * v1.x + (hUn1.x - hn1.x) + (wLn1.x - wn1.x);
    float gy1 = sc1 * v1.y + (hUn1.y - hn1.y) + (wLn1.y - wn1.y);
    float2 xold0 = bits2f(xh_u.x), xold1 = bits2f(xh_u.y);
    float2 xn0 = make_float2(xold0.x - TAU * gx0, xold0.y - TAU * gy0);
    float2 xn1 = make_float2(xold1.x - TAU * gx1, xold1.y - TAU * gy1);
    float2 xb20 = make_float2(2.0f * xn0.x - xold0.x, 2.0f * xn0.y - xold0.y);
    float2 xb21 = make_float2(2.0f * xn1.x - xold1.x, 2.0f * xn1.y - xold1.y);
    // -------- pair stores --------
    uint2 su;
    su.x = h2bits(hn0);  su.y = h2bits(hn1);  *reinterpret_cast<uint2*>(p2h_d + ib + c0) = su;
    su.x = h2bits(wn0);  su.y = h2bits(wn1);  *reinterpret_cast<uint2*>(p2w_d + ib + c0) = su;
    su.x = h2bits(xn0);  su.y = h2bits(xn1);  *reinterpret_cast<uint2*>(xh   + ib + c0) = su;
    su.x = h2bits(xb20); su.y = h2bits(xb21); *reinterpret_cast<uint2*>(xb_d + ib + c0) = su;
    if(last){
      float4 o = make_float4(xn0.x, xn0.y, xn1.x, xn1.y);
      *reinterpret_cast<float4*>(xout + ib + c0) = o;
    }
    lds[rr * LSTRIDE + SL(c0)]     = make_float2(sc0 * xb20.x, sc0 * xb20.y);
    lds[rr * LSTRIDE + SL(c0 + 1)] = make_float2(sc1 * xb21.x, sc1 * xb21.y);
  }
  if(last) return;
  __syncthreads();
  fft_fwd_pair(&lds[wv * LSTRIDE], &lds[(wv + 4) * LSTRIDE], l, twid);
  __syncthreads();
  store_strip_blk(lds, U + ((size_t)(b * 64 + rb) << 12), t);
}

// ---------------- init kernels ---------------------------------------------------------------
__global__ __launch_bounds__(256) void k_init_x(const float* __restrict__ ir, const float* __restrict__ ii,
                                                __half2* __restrict__ xh, __half2* __restrict__ xb0){
  int i = blockIdx.x * 256 + threadIdx.x;
  __half2 v = __floats2half2_rn(ir[i], ii[i]);
  xh[i] = v; xb0[i] = v;
}

__global__ __launch_bounds__(256) void k_init_lam(const float* __restrict__ lam, __half* __restrict__ lamh){
  int i = blockIdx.x * 256 + threadIdx.x;
  lamh[i] = __float2half(lam[i]);
}

__global__ __launch_bounds__(256) void k_init_tw(float2* __restrict__ tw){
  int i = blockIdx.x * 256 + threadIdx.x;
  if(i < 512){
    int l = i >> 3, t = i & 7;
    float th = -6.283185307179586f * (float)(l * t) / 512.0f;
    tw[i] = make_float2(cosf(th), sinf(th));
  } else if(i < 576){
    int j = i - 512; int m = j >> 3, t = j & 7;
    float th = -6.283185307179586f * (float)(m * t) / 64.0f;
    tw[i] = make_float2(cosf(th), sinf(th));
  }
}

// Build per-column packed index list + packed y' (digit-rev, S-folded, fp16) for active entries.
__global__ __launch_bounds__(256) void k_pack(const int* __restrict__ mask, const float* __restrict__ kr,
                                              const float* __restrict__ ki, int* __restrict__ idx,
                                              int* __restrict__ cnt, __half2* __restrict__ yp){
  __shared__ int wcnt[8];
  int cs = blockIdx.x;
  int t = threadIdx.x, lane = t & 63, wv = t >> 6;
  int csr = rev9(cs);
  int jbase = cs << 9;
  #pragma unroll
  for(int rnd = 0; rnd < 2; rnd++){
    int ks = t + 256 * rnd;
    int ksr = rev9(ks);
    int pred = (mask[(ksr << 9) + csr] != 0) ? 1 : 0;
    unsigned long long bal = __ballot(pred);
    if(lane == 0) wcnt[4 * rnd + wv] = (int)__popcll(bal);
    __syncthreads();
    int pre = 0;
    for(int w = 0; w < wv; w++) pre += wcnt[4 * rnd + w];
    int roundbase = (rnd == 1) ? (wcnt[0] + wcnt[1] + wcnt[2] + wcnt[3]) : 0;
    int lpre = (int)__popcll(bal & ((1ull << lane) - 1ull));
    if(pred){
      int pos = jbase + roundbase + pre + lpre;
      idx[pos] = ks;
      float s = ((ksr + csr) & 1) ? -1.0f : 1.0f;
      for(int b = 0; b < 16; b++){
        size_t a = ((size_t)b << 18) + ((size_t)ksr << 9) + csr;
        yp[(size_t)b * APACK + pos] = __floats2half2_rn(s * kr[a], s * ki[a]);
      }
    }
    __syncthreads();
  }
  if(t == 0) cnt[cs] = wcnt[0] + wcnt[1] + wcnt[2] + wcnt[3] + wcnt[4] + wcnt[5] + wcnt[6] + wcnt[7];
}

// ---------------- launcher -------------------------------------------------------------------
extern "C" void kernel_launch(void* const* d_in, const int* in_sizes, int n_in,
                              void* d_out, int out_size, void* d_ws, size_t ws_size,
                              hipStream_t stream){
  const float* ir  = (const float*)d_in[0];
  const float* ii  = (const float*)d_in[1];
  const float* kdr = (const float*)d_in[2];
  const float* kdi = (const float*)d_in[3];
  const float* lam = (const float*)d_in[4];
  const int*  mask = (const int*)d_in[5];
  float2* x = (float2*)d_out;

  char* ws = (char*)d_ws;
  __half2* p1p   = (__half2*)ws;                     // 16 MB
  __half2* yp    = p1p + (size_t)APACK * 16;         // 16 MB
  __half2* p2h0  = yp  + (size_t)APACK * 16;         // 16 MB  (zeroed; contiguous w/ p2w0)
  __half2* p2w0  = p2h0 + NT;                        // 16 MB
  __half2* p2h1  = p2w0 + NT;                        // 16 MB
  __half2* p2w1  = p2h1 + NT;                        // 16 MB
  __half2* xb0   = p2w1 + NT;                        // 16 MB
  __half2* xb1   = xb0 + NT;                         // 16 MB
  __half2* xh    = xb1 + NT;                         // 16 MB (fp16 primal state)
  __half2* U     = xh  + NT;                         // 16 MB (blocked tiles)
  __half2* V     = U   + NT;                         // 16 MB (blocked tiles)
  __half*  lamh  = (__half*)(V + NT);                // 8 MB
  int*     idx   = (int*)(lamh + NT);                // 1 MB
  int*     cnt   = idx + APACK;                      // 2 KB
  float2*  twid  = (float2*)(cnt + 512);             // 4.6 KB twiddle table
  // total ws use: ~185 MB

  hipMemsetAsync(p1p, 0, (size_t)APACK * 16 * sizeof(__half2), stream);   // p1 = 0
  hipMemsetAsync(p2h0, 0, (size_t)2 * NT * sizeof(__half2), stream);      // p2h0 + p2w0 = 0
  k_init_tw<<<3, 256, 0, stream>>>(twid);
  k_pack<<<512, 256, 0, stream>>>(mask, kdr, kdi, idx, cnt, yp);
  k_init_lam<<<NT / 256, 256, 0, stream>>>(lam, lamh);
  k_init_x<<<NT / 256, 256, 0, stream>>>(ir, ii, xh, xb0);
  k_fwd_rows<<<1024, 256, 0, stream>>>(ir, ii, U, twid);

  __half2* p2hs[2] = {p2h0, p2h1};
  __half2* p2ws[2] = {p2w0, p2w1};
  __half2* xbs[2]  = {xb0, xb1};

  for(int it = 0; it < 128; it++){
    int s = it & 1, d = s ^ 1;
    k_colsA<<<1024, 256, 0, stream>>>(U, p1p, yp, idx, cnt, V, twid);
    k_megaB<<<1024, 256, 0, stream>>>(V, p2hs[s], p2ws[s], p2hs[d], p2ws[d],
                                      xbs[s], xbs[d], xh, lamh, U, x, twid, it == 127 ? 1 : 0);
  }
}